// Round 3
// baseline (170.706 us; speedup 1.0000x reference)
//
#include <hip/hip_runtime.h>
#include <math.h>

// DigitCaps2: B=128, C=1024 in_caps, I=16 in_dim, N=16 num_caps, D=16 dim_caps
#define NB 128
#define NC 1024
#define NN 16
#define ND 16
#define NI 16
#define COEF 0.25f

typedef __attribute__((ext_vector_type(8))) short short8;
typedef __attribute__((ext_vector_type(4))) float f32x4;
typedef unsigned short ushort_t;

__device__ __forceinline__ unsigned short f2bf(float f) {
  unsigned int u = __builtin_bit_cast(unsigned int, f);
  u += 0x7fffu + ((u >> 16) & 1u);
  return (unsigned short)(u >> 16);
}
__device__ __forceinline__ float bf2f(unsigned short u) {
  unsigned int v = ((unsigned int)u) << 16;
  return __builtin_bit_cast(float, v);
}

// K1: convert x (262144 groups of 8) and W (524288 groups) to bf16; zero counters.
__global__ __launch_bounds__(256) void k_prep(const float4* __restrict__ x,
                                              const float4* __restrict__ W,
                                              ushort_t* __restrict__ xb,
                                              ushort_t* __restrict__ Wb,
                                              int* __restrict__ counters) {
  int id = blockIdx.x * 256 + threadIdx.x;
  if (blockIdx.x == 0 && threadIdx.x < 128) counters[threadIdx.x] = 0;
  const float4* src;
  ushort_t* dst;
  int k;
  if (id < 262144) { src = x; dst = xb; k = id; }
  else { src = W; dst = Wb; k = id - 262144; }
  float4 a = src[2 * k], b = src[2 * k + 1];
  short8 o;
  o[0] = (short)f2bf(a.x); o[1] = (short)f2bf(a.y);
  o[2] = (short)f2bf(a.z); o[3] = (short)f2bf(a.w);
  o[4] = (short)f2bf(b.x); o[5] = (short)f2bf(b.y);
  o[6] = (short)f2bf(b.z); o[7] = (short)f2bf(b.w);
  *(short8*)(dst + (size_t)k * 8) = o;
}

// K2: usum partials + last-block-per-(n,bt) reduction -> usum[n][b][d].
// block = n*64 + bt*8 + kcg; wave w handles kc = kcg*4+w (32 c's, 16 K=32 MFMA).
__global__ __launch_bounds__(256) void k_usum(const ushort_t* __restrict__ xb,
                                              const ushort_t* __restrict__ Wb,
                                              float* __restrict__ part,
                                              float* __restrict__ usum,
                                              int* __restrict__ counters) {
  int bx = blockIdx.x;
  int n = bx >> 6, bt = (bx >> 3) & 7, kcg = bx & 7;
  int w = threadIdx.x >> 6, l = threadIdx.x & 63;
  int kc = kcg * 4 + w;
  int q = l >> 4, b16 = l & 15;
  int c0 = kc * 32;
  const ushort_t* ap = Wb + (((size_t)(n * NC + c0 + (q >> 1)) * ND + b16) * NI) + (q & 1) * 8;
  const ushort_t* bp = xb + (size_t)(bt * 16 + b16) * (NC * NI) + (c0 + (q >> 1)) * NI + (q & 1) * 8;
  f32x4 acc = {0.f, 0.f, 0.f, 0.f};
#pragma unroll
  for (int s = 0; s < 16; ++s) {
    short8 av = *(const short8*)ap;
    short8 bv = *(const short8*)bp;
    acc = __builtin_amdgcn_mfma_f32_16x16x32_bf16(av, bv, acc, 0, 0, 0);
    ap += 2 * ND * NI;
    bp += 2 * NI;
  }
  // part[n][bt][kc][b16][d], d rows = q*4+r
  *(f32x4*)(part + ((size_t)((n * 8 + bt) * 32 + kc)) * 256 + b16 * 16 + q * 4) = acc;

  __shared__ int isLast;
  __syncthreads();
  if (threadIdx.x == 0) {
    __threadfence();
    int old = atomicAdd(&counters[n * 8 + bt], 1);
    isLast = (old == 7) ? 1 : 0;
  }
  __syncthreads();
  if (isLast) {
    __threadfence();
    int t = threadIdx.x;  // t = b16r*16 + d
    float s = 0.f;
    const float* pp = part + ((size_t)((n * 8 + bt) * 32)) * 256 + t;
    for (int k2 = 0; k2 < 32; ++k2) { s += *pp; pp += 256; }
    usum[((size_t)n * NB + bt * 16 + (t >> 4)) * ND + (t & 15)] = s;
    if (threadIdx.x == 0) counters[n * 8 + bt] = 0;
  }
}

// K3: fused scores + softmax + weighted-sum partials.
// block = bt*32 + cc (256 blocks x 1024 threads); wave = n.
__global__ __launch_bounds__(1024) void k_bc(const ushort_t* __restrict__ xb,
                                             const ushort_t* __restrict__ Wb,
                                             const float* __restrict__ usum,
                                             const float* __restrict__ Bbias,
                                             float* __restrict__ part) {
  __shared__ float scl[NN * 32 * 16];  // [n][c][b16], 32 KB
  int bx = blockIdx.x;
  int bt = bx >> 5, cc = bx & 31;
  int n = threadIdx.x >> 6, l = threadIdx.x & 63;
  int q = l >> 4, b16 = l & 15;
  int c0 = cc * 32;

  // phase 1: scores[n][c][b] = COEF * sum_d usum[b,n,d] * u_hat[b,n,c,d]
  f32x4 us = *(const f32x4*)(usum + ((size_t)n * NB + bt * 16 + b16) * ND + q * 4);
  {
    const ushort_t* ap = Wb + (((size_t)(n * NC + c0) * ND + b16) * NI) + (q & 1) * 8;
    const ushort_t* bp = xb + (size_t)(bt * 16 + b16) * (NC * NI) + c0 * NI + (q & 1) * 8;
    for (int c = 0; c < 32; ++c) {
      short8 av = {0, 0, 0, 0, 0, 0, 0, 0};
      short8 bv = {0, 0, 0, 0, 0, 0, 0, 0};
      if (q < 2) {
        av = *(const short8*)ap;
        bv = *(const short8*)bp;
      }
      f32x4 z = {0.f, 0.f, 0.f, 0.f};
      f32x4 d = __builtin_amdgcn_mfma_f32_16x16x32_bf16(av, bv, z, 0, 0, 0);
      float v = us[0] * d[0] + us[1] * d[1] + us[2] * d[2] + us[3] * d[3];
      v += __shfl_xor(v, 16);
      v += __shfl_xor(v, 32);
      if (q == 0) scl[(n * 32 + c) * 16 + b16] = COEF * v;
      ap += ND * NI;
      bp += NI;
    }
  }
  __syncthreads();

  // phase 2: softmax over n + bias, in place (thread owns (c,b) column)
  if (threadIdx.x < 512) {
    int c = threadIdx.x >> 4, b = threadIdx.x & 15;
    float v[NN];
    float m = -1e30f;
#pragma unroll
    for (int k = 0; k < NN; ++k) {
      v[k] = scl[(k * 32 + c) * 16 + b];
      m = fmaxf(m, v[k]);
    }
    float sum = 0.f;
#pragma unroll
    for (int k = 0; k < NN; ++k) {
      v[k] = expf(v[k] - m);
      sum += v[k];
    }
    float inv = 1.0f / sum;
#pragma unroll
    for (int k = 0; k < NN; ++k) {
      scl[(k * 32 + c) * 16 + b] = v[k] * inv + Bbias[k * NC + c0 + c];
    }
  }
  __syncthreads();

  // phase 3: s partials with coef from LDS
  f32x4 acc = {0.f, 0.f, 0.f, 0.f};
  const ushort_t* ap = Wb + (((size_t)(n * NC + c0 + (q >> 1)) * ND + b16) * NI) + (q & 1) * 8;
  const ushort_t* bp = xb + (size_t)(bt * 16 + b16) * (NC * NI) + (c0 + (q >> 1)) * NI + (q & 1) * 8;
  const float* cp = &scl[(n * 32 + (q >> 1)) * 16 + b16];
#pragma unroll
  for (int s = 0; s < 16; ++s) {
    short8 av = *(const short8*)ap;
    short8 xv = *(const short8*)bp;
    float cf = *cp;
    short8 bv;
#pragma unroll
    for (int j = 0; j < 8; ++j) bv[j] = (short)f2bf(bf2f((unsigned short)xv[j]) * cf);
    acc = __builtin_amdgcn_mfma_f32_16x16x32_bf16(av, bv, acc, 0, 0, 0);
    ap += 2 * ND * NI;
    bp += 2 * NI;
    cp += 2 * 16;
  }
  *(f32x4*)(part + ((size_t)((n * 8 + bt) * 32 + cc)) * 256 + b16 * 16 + q * 4) = acc;
}

// K4: reduce s partials over kc + squash -> out[b][n][d]. thread = (b,n,dq).
__global__ __launch_bounds__(256) void k_fin(const float* __restrict__ part,
                                             float* __restrict__ out) {
  int id = blockIdx.x * 256 + threadIdx.x;  // 8192 = b*64 + n*4 + dq
  int dq = id & 3, n = (id >> 2) & 15, b = id >> 6;
  int bt = b >> 4, b16 = b & 15;
  f32x4 sv = {0.f, 0.f, 0.f, 0.f};
  const float* pp = part + ((size_t)((n * 8 + bt) * 32)) * 256 + b16 * 16 + dq * 4;
  for (int kc = 0; kc < 32; ++kc) {
    f32x4 p = *(const f32x4*)pp;
    sv += p;
    pp += 256;
  }
  float sq = sv[0] * sv[0] + sv[1] * sv[1] + sv[2] * sv[2] + sv[3] * sv[3];
  sq += __shfl_xor(sq, 1);
  sq += __shfl_xor(sq, 2);
  float norm = sqrtf(sq);
  float scale = (1.0f - expf(-norm)) / sqrtf(sq + 1e-8f);
  f32x4 o = {sv[0] * scale, sv[1] * scale, sv[2] * scale, sv[3] * scale};
  *(f32x4*)(out + (size_t)id * 4) = o;
}

extern "C" void kernel_launch(void* const* d_in, const int* in_sizes, int n_in,
                              void* d_out, int out_size, void* d_ws, size_t ws_size,
                              hipStream_t stream) {
  const float* x = (const float*)d_in[0];   // [128][1024][16]
  const float* W = (const float*)d_in[1];   // [1][16][1024][16][16]
  const float* Bb = (const float*)d_in[2];  // [16][1][1024]
  float* out = (float*)d_out;               // [128][16][16]
  float* ws = (float*)d_ws;

  // ws layout (float units): ~16.9 MB total
  ushort_t* xb = (ushort_t*)ws;              // 2,097,152 bf16 = 1,048,576 f
  ushort_t* Wb = (ushort_t*)(ws + 1048576);  // 4,194,304 bf16 = 2,097,152 f
  float* part = ws + 1048576 + 2097152;      // [16][8][32][256] = 1,048,576 f
  float* usum = part + 1048576;              // [16][128][16] = 32,768 f
  int* counters = (int*)(usum + 32768);      // 128 ints

  hipLaunchKernelGGL(k_prep, dim3(3072), dim3(256), 0, stream,
                     (const float4*)x, (const float4*)W, xb, Wb, counters);
  hipLaunchKernelGGL(k_usum, dim3(1024), dim3(256), 0, stream, xb, Wb, part, usum, counters);
  hipLaunchKernelGGL(k_bc, dim3(256), dim3(1024), 0, stream, xb, Wb, usum, Bb, part);
  hipLaunchKernelGGL(k_fin, dim3(32), dim3(256), 0, stream, part, out);
}

// Round 4
// 63.320 us; speedup vs baseline: 2.6959x; 2.6959x over previous
//
#include <hip/hip_runtime.h>
#include <math.h>

// DigitCaps2: B=128, C=1024 in_caps, I=16 in_dim, N=16 num_caps, D=16 dim_caps
#define NB 128
#define NC 1024
#define NN 16
#define ND 16
#define NI 16
#define COEF 0.25f

typedef __attribute__((ext_vector_type(8))) short short8;
typedef __attribute__((ext_vector_type(4))) float f32x4;
typedef unsigned short ushort_t;

__device__ __forceinline__ unsigned short f2bf(float f) {
  unsigned int u = __builtin_bit_cast(unsigned int, f);
  u += 0x7fffu + ((u >> 16) & 1u);
  return (unsigned short)(u >> 16);
}
__device__ __forceinline__ float bf2f(unsigned short u) {
  unsigned int v = ((unsigned int)u) << 16;
  return __builtin_bit_cast(float, v);
}

// K1: convert x (262144 groups of 8) and W (524288 groups) to bf16.
__global__ __launch_bounds__(256) void k_prep(const float4* __restrict__ x,
                                              const float4* __restrict__ W,
                                              ushort_t* __restrict__ xb,
                                              ushort_t* __restrict__ Wb) {
  int id = blockIdx.x * 256 + threadIdx.x;
  const float4* src;
  ushort_t* dst;
  int k;
  if (id < 262144) { src = x; dst = xb; k = id; }
  else { src = W; dst = Wb; k = id - 262144; }
  float4 a = src[2 * k], b = src[2 * k + 1];
  short8 o;
  o[0] = (short)f2bf(a.x); o[1] = (short)f2bf(a.y);
  o[2] = (short)f2bf(a.z); o[3] = (short)f2bf(a.w);
  o[4] = (short)f2bf(b.x); o[5] = (short)f2bf(b.y);
  o[6] = (short)f2bf(b.z); o[7] = (short)f2bf(b.w);
  *(short8*)(dst + (size_t)k * 8) = o;
}

// K2: usum[n][b][d] in one kernel. block = (n, bt), 16 waves; wave w owns
// c in [w*64, w*64+64) -> 32 K=32 MFMA steps; LDS reduce across waves.
__global__ __launch_bounds__(1024) void k_usum(const ushort_t* __restrict__ xb,
                                               const ushort_t* __restrict__ Wb,
                                               float* __restrict__ usum) {
  __shared__ f32x4 red[16][64];  // 16 KB
  int bx = blockIdx.x;
  int n = bx >> 3, bt = bx & 7;
  int w = threadIdx.x >> 6, l = threadIdx.x & 63;
  int q = l >> 4, b16 = l & 15;
  int c0 = w * 64;
  const ushort_t* ap = Wb + (((size_t)(n * NC + c0 + (q >> 1)) * ND + b16) * NI) + (q & 1) * 8;
  const ushort_t* bp = xb + (size_t)(bt * 16 + b16) * (NC * NI) + (c0 + (q >> 1)) * NI + (q & 1) * 8;
  f32x4 acc = {0.f, 0.f, 0.f, 0.f};
#pragma unroll
  for (int s = 0; s < 32; ++s) {
    short8 av = *(const short8*)ap;
    short8 bv = *(const short8*)bp;
    acc = __builtin_amdgcn_mfma_f32_16x16x32_bf16(av, bv, acc, 0, 0, 0);
    ap += 2 * ND * NI;
    bp += 2 * NI;
  }
  red[w][l] = acc;
  __syncthreads();
  if (threadIdx.x < 64) {
    f32x4 t = red[0][l];
#pragma unroll
    for (int k = 1; k < 16; ++k) t += red[k][l];
    // lane l = (q,b16) holds D[d=q*4+r][b=b16]
    *(f32x4*)(usum + ((size_t)n * NB + bt * 16 + b16) * ND + q * 4) = t;
  }
}

// K3: fused scores + softmax + weighted-sum partials.
// block = bt*32 + cc (256 blocks x 1024 threads); wave = n.
__global__ __launch_bounds__(1024) void k_bc(const ushort_t* __restrict__ xb,
                                             const ushort_t* __restrict__ Wb,
                                             const float* __restrict__ usum,
                                             const float* __restrict__ Bbias,
                                             float* __restrict__ part) {
  __shared__ float scl[NN * 32 * 16];  // [n][c][b16], 32 KB
  int bx = blockIdx.x;
  int bt = bx >> 5, cc = bx & 31;
  int n = threadIdx.x >> 6, l = threadIdx.x & 63;
  int q = l >> 4, b16 = l & 15;
  int c0 = cc * 32;

  // phase 1: scores[n][c][b] = COEF * sum_d usum[b,n,d] * u_hat[b,n,c,d]
  f32x4 us = *(const f32x4*)(usum + ((size_t)n * NB + bt * 16 + b16) * ND + q * 4);
  {
    const ushort_t* ap = Wb + (((size_t)(n * NC + c0) * ND + b16) * NI) + (q & 1) * 8;
    const ushort_t* bp = xb + (size_t)(bt * 16 + b16) * (NC * NI) + c0 * NI + (q & 1) * 8;
    for (int c = 0; c < 32; ++c) {
      short8 av = {0, 0, 0, 0, 0, 0, 0, 0};
      short8 bv = {0, 0, 0, 0, 0, 0, 0, 0};
      if (q < 2) {
        av = *(const short8*)ap;
        bv = *(const short8*)bp;
      }
      f32x4 z = {0.f, 0.f, 0.f, 0.f};
      f32x4 d = __builtin_amdgcn_mfma_f32_16x16x32_bf16(av, bv, z, 0, 0, 0);
      float v = us[0] * d[0] + us[1] * d[1] + us[2] * d[2] + us[3] * d[3];
      v += __shfl_xor(v, 16);
      v += __shfl_xor(v, 32);
      if (q == 0) scl[(n * 32 + c) * 16 + b16] = COEF * v;
      ap += ND * NI;
      bp += NI;
    }
  }
  __syncthreads();

  // phase 2: softmax over n + bias, in place (thread owns (c,b) column)
  if (threadIdx.x < 512) {
    int c = threadIdx.x >> 4, b = threadIdx.x & 15;
    float v[NN];
    float m = -1e30f;
#pragma unroll
    for (int k = 0; k < NN; ++k) {
      v[k] = scl[(k * 32 + c) * 16 + b];
      m = fmaxf(m, v[k]);
    }
    float sum = 0.f;
#pragma unroll
    for (int k = 0; k < NN; ++k) {
      v[k] = expf(v[k] - m);
      sum += v[k];
    }
    float inv = 1.0f / sum;
#pragma unroll
    for (int k = 0; k < NN; ++k) {
      scl[(k * 32 + c) * 16 + b] = v[k] * inv + Bbias[k * NC + c0 + c];
    }
  }
  __syncthreads();

  // phase 3: s partials with coef from LDS
  f32x4 acc = {0.f, 0.f, 0.f, 0.f};
  const ushort_t* ap = Wb + (((size_t)(n * NC + c0 + (q >> 1)) * ND + b16) * NI) + (q & 1) * 8;
  const ushort_t* bp = xb + (size_t)(bt * 16 + b16) * (NC * NI) + (c0 + (q >> 1)) * NI + (q & 1) * 8;
  const float* cp = &scl[(n * 32 + (q >> 1)) * 16 + b16];
#pragma unroll
  for (int s = 0; s < 16; ++s) {
    short8 av = *(const short8*)ap;
    short8 xv = *(const short8*)bp;
    float cf = *cp;
    short8 bv;
#pragma unroll
    for (int j = 0; j < 8; ++j) bv[j] = (short)f2bf(bf2f((unsigned short)xv[j]) * cf);
    acc = __builtin_amdgcn_mfma_f32_16x16x32_bf16(av, bv, acc, 0, 0, 0);
    ap += 2 * ND * NI;
    bp += 2 * NI;
    cp += 2 * 16;
  }
  *(f32x4*)(part + ((size_t)((n * 8 + bt) * 32 + cc)) * 256 + b16 * 16 + q * 4) = acc;
}

// K4: reduce s partials over cc + squash -> out[b][n][d]. thread = (b,n,dq).
__global__ __launch_bounds__(256) void k_fin(const float* __restrict__ part,
                                             float* __restrict__ out) {
  int id = blockIdx.x * 256 + threadIdx.x;  // 8192 = b*64 + n*4 + dq
  int dq = id & 3, n = (id >> 2) & 15, b = id >> 6;
  int bt = b >> 4, b16 = b & 15;
  f32x4 sv = {0.f, 0.f, 0.f, 0.f};
  const float* pp = part + ((size_t)((n * 8 + bt) * 32)) * 256 + b16 * 16 + dq * 4;
  for (int kc = 0; kc < 32; ++kc) {
    f32x4 p = *(const f32x4*)pp;
    sv += p;
    pp += 256;
  }
  float sq = sv[0] * sv[0] + sv[1] * sv[1] + sv[2] * sv[2] + sv[3] * sv[3];
  sq += __shfl_xor(sq, 1);
  sq += __shfl_xor(sq, 2);
  float norm = sqrtf(sq);
  float scale = (1.0f - expf(-norm)) / sqrtf(sq + 1e-8f);
  f32x4 o = {sv[0] * scale, sv[1] * scale, sv[2] * scale, sv[3] * scale};
  *(f32x4*)(out + (size_t)id * 4) = o;
}

extern "C" void kernel_launch(void* const* d_in, const int* in_sizes, int n_in,
                              void* d_out, int out_size, void* d_ws, size_t ws_size,
                              hipStream_t stream) {
  const float* x = (const float*)d_in[0];   // [128][1024][16]
  const float* W = (const float*)d_in[1];   // [1][16][1024][16][16]
  const float* Bb = (const float*)d_in[2];  // [16][1][1024]
  float* out = (float*)d_out;               // [128][16][16]
  float* ws = (float*)d_ws;

  // ws layout (float units): ~16.9 MB total
  ushort_t* xb = (ushort_t*)ws;              // 2,097,152 bf16 = 1,048,576 f
  ushort_t* Wb = (ushort_t*)(ws + 1048576);  // 4,194,304 bf16 = 2,097,152 f
  float* part = ws + 1048576 + 2097152;      // [16][8][32][256] = 1,048,576 f
  float* usum = part + 1048576;              // [16][128][16] = 32,768 f

  hipLaunchKernelGGL(k_prep, dim3(3072), dim3(256), 0, stream,
                     (const float4*)x, (const float4*)W, xb, Wb);
  hipLaunchKernelGGL(k_usum, dim3(128), dim3(1024), 0, stream, xb, Wb, usum);
  hipLaunchKernelGGL(k_bc, dim3(256), dim3(1024), 0, stream, xb, Wb, usum, Bb, part);
  hipLaunchKernelGGL(k_fin, dim3(32), dim3(256), 0, stream, part, out);
}